// Round 5
// baseline (83.291 us; speedup 1.0000x reference)
//
#include <hip/hip_runtime.h>
#include <hip/hip_cooperative_groups.h>
#include <cmath>

namespace cg = cooperative_groups;

// AGD loss: for each of n=32768 rows (view-major flatten of [B,2,128] features),
// evaluate the truncated Saw series at the first 100 coordinates, sum, gather
// the label coordinate's value, accumulate log(sum) - log(s_lab).
// The exp(log_Cd - 1/(2*var)) prefactor cancels between the two logs.
// NT=20 (vs reference 40): term_n ~ (y*sqrt(d))^n/n!, worst |y*sqrt(d)|~6.0
// -> tail at n=20 ~ 1.5e-3 abs vs s ~ 400 -> rel ~ 4e-6. Threshold is 2%.
//
// Structure notes:
//  - round-3 lesson: NO same-address global atomics (1024 cost ~17 us serial).
//  - round-4 lesson: the two-dispatch structure spends ~5-6 us in node/launch
//    gaps, more than either kernel's execution. Fuse into ONE cooperative
//    kernel: block partials -> d_ws, grid.sync(), block 0 reduces -> out[0].

#define BQ     16384   // batch
#define NROWS  32768   // V*B
#define NT     20      // truncated series terms

struct Coefs { float c[NT]; };

// 8 threads per row. Lane phase p = tid&7.
// Coords 0..95 as 24 float4 chunks: lane p owns chunks {p, p+8, p+16}.
// 13th poly: lanes p<4 evaluate coord 96+p, lanes p>=4 evaluate the label
// coord (same instruction stream, no divergence, no redundant label work).
__global__ __launch_bounds__(256) void agd_fused_kernel(
    const float* __restrict__ feats,    // [B, 2, 128]
    const int*   __restrict__ labels,   // [B]
    float*       __restrict__ partials, // [1024] in d_ws
    float*       __restrict__ out,      // [1]
    Coefs C)
{
    const int tid = threadIdx.x;
    const int p   = tid & 7;
    const int j   = blockIdx.x * 32 + (tid >> 3);   // global row, 32 rows/block
    const int b   = j & (BQ - 1);
    const int v   = j >> 14;
    const float*  row  = feats + ((size_t)(b * 2 + v) << 7);
    const float4* row4 = (const float4*)row;
    const int lab = labels[b];

    float sum_s = 0.0f;
    #pragma unroll
    for (int i = 0; i < 3; ++i) {
        const float4 yv = row4[p + 8 * i];   // lanes 0..7 -> 128 contiguous B
        float s0 = C.c[NT - 1], s1 = s0, s2 = s0, s3 = s0;
        #pragma unroll
        for (int k = NT - 2; k >= 0; --k) {
            s0 = fmaf(s0, yv.x, C.c[k]);
            s1 = fmaf(s1, yv.y, C.c[k]);
            s2 = fmaf(s2, yv.z, C.c[k]);
            s3 = fmaf(s3, yv.w, C.c[k]);
        }
        sum_s += (s0 + s1) + (s2 + s3);
    }

    // 13th polynomial, balanced across lanes
    const float y13 = (p < 4) ? row[96 + p] : row[lab];
    float s13 = C.c[NT - 1];
    #pragma unroll
    for (int k = NT - 2; k >= 0; --k) s13 = fmaf(s13, y13, C.c[k]);
    if (p < 4) sum_s += s13;             // coords 96..99 join the norm sum

    // reduce sum_s across the 8 lanes of this row (bits 0..2)
    sum_s += __shfl_xor(sum_s, 1);
    sum_s += __shfl_xor(sum_s, 2);
    sum_s += __shfl_xor(sum_s, 4);

    // bring the label-poly value (held by lanes p>=4) to lanes p<4
    const float s_lab = __shfl_xor(s13, 4);

    // per-row loss term on phase-0 lanes only
    float term = (p == 0) ? (logf(sum_s) - logf(s_lab)) : 0.0f;

    // wave butterfly over the 8 rows in this wave (bits 3..5)
    term += __shfl_xor(term, 8);
    term += __shfl_xor(term, 16);
    term += __shfl_xor(term, 32);

    __shared__ float wsum[4];
    const int wave = tid >> 6;
    if ((tid & 63) == 0) wsum[wave] = term;
    __syncthreads();
    if (tid == 0) partials[blockIdx.x] = (wsum[0] + wsum[1]) + (wsum[2] + wsum[3]);

    // ---- grid-wide sync, then block 0 reduces the 1024 partials ----
    cg::this_grid().sync();

    if (blockIdx.x == 0) {
        const float4 v4 = ((const float4*)partials)[tid];
        float s = (v4.x + v4.y) + (v4.z + v4.w);
        s += __shfl_xor(s, 1);
        s += __shfl_xor(s, 2);
        s += __shfl_xor(s, 4);
        s += __shfl_xor(s, 8);
        s += __shfl_xor(s, 16);
        s += __shfl_xor(s, 32);
        __shared__ float w2[4];
        if ((tid & 63) == 0) w2[tid >> 6] = s;
        __syncthreads();
        if (tid == 0) out[0] = (w2[0] + w2[1]) + (w2[2] + w2[3]);
    }
}

extern "C" void kernel_launch(void* const* d_in, const int* in_sizes, int n_in,
                              void* d_out, int out_size, void* d_ws, size_t ws_size,
                              hipStream_t stream) {
    (void)in_sizes; (void)n_in; (void)out_size; (void)ws_size;
    const float* feats  = (const float*)d_in[0];
    const int*   labels = (const int*)d_in[1];
    float*       out    = (float*)d_out;
    float*       partials = (float*)d_ws;   // 1024 floats = 4 KB of scratch

    // Saw series coefficients c_n = 2^{n/2} Gamma((d+n)/2) / Gamma(d/2) / n!,
    // d = 128, computed in double on host, passed by value (capture-safe).
    Coefs C;
    for (int n = 0; n < NT; ++n) {
        const double ln = 0.5 * n * std::log(2.0)
                        + std::lgamma((128.0 + n) / 2.0)
                        - std::lgamma(64.0)
                        - std::lgamma(n + 1.0);
        C.c[n] = (float)std::exp(ln);
    }

    // 8 threads/row * 32768 rows / 256 threads = 1024 blocks
    // (4 blocks/CU, 16 waves/CU -- co-resident, cooperative-safe)
    void* args[] = { (void*)&feats, (void*)&labels, (void*)&partials,
                     (void*)&out, (void*)&C };
    hipLaunchCooperativeKernel((const void*)agd_fused_kernel,
                               dim3(1024), dim3(256), args, 0, stream);
}

// Round 6
// 26.473 us; speedup vs baseline: 3.1463x; 3.1463x over previous
//
#include <hip/hip_runtime.h>
#include <cmath>

// AGD loss: for each of n=32768 rows (view-major flatten of [B,2,128] features),
// evaluate the truncated Saw series at the first 100 coordinates, sum, gather
// the label coordinate's value, accumulate log(sum) - log(s_lab).
// The exp(log_Cd - 1/(2*var)) prefactor cancels between the two logs.
// NT=20 (vs reference 40): term_n ~ (y*sqrt(d))^n/n!, worst |y*sqrt(d)|~6.0
// -> tail at n=20 ~ 1.5e-3 abs vs s ~ 400 -> rel ~ 4e-6. Threshold is 2%.
//
// Structure lessons so far:
//  - r3: 1024 same-address atomicAdds serialize (~17 ns each) = +17 us. Never.
//  - r4: two-kernel structure = 11.0 us, ~6 us of it node dispatch overhead.
//  - r5: cg::this_grid().sync() costs ~65 us on MI355X. Never.
// This round: SINGLE kernel node, no memset, no grid sync. Last-block-done
// arrival using monotone counters + "(old & 31)==31" trigger, which fires
// exactly once per 32 increments REGARDLESS of the counter's start value —
// poison-proof (0xAA), correctness-call-proof, replay-accumulation-proof.
// Hierarchical: 32 sub-counters (64B apart, parallel) -> 1 master counter.
// Winner block acquire-fences and reduces the 1024 partials -> out[0].

#define BQ     16384   // batch
#define NROWS  32768   // V*B
#define NT     20      // truncated series terms
#define NBLK   1024

struct Coefs { float c[NT]; };

// d_ws layout (floats):  [0..1023]   block partials
//                        [1024.. ]   counters: sub[g] at uint index g*16
//                                    (64B apart), master at uint index 512.
__global__ __launch_bounds__(256) void agd_onepass_kernel(
    const float* __restrict__ feats,    // [B, 2, 128]
    const int*   __restrict__ labels,   // [B]
    float*       __restrict__ ws,       // d_ws
    float*       __restrict__ out,      // [1]
    Coefs C)
{
    const int tid = threadIdx.x;
    const int p   = tid & 7;
    const int j   = blockIdx.x * 32 + (tid >> 3);   // global row, 32 rows/block
    const int b   = j & (BQ - 1);
    const int v   = j >> 14;
    const float*  row  = feats + ((size_t)(b * 2 + v) << 7);
    const float4* row4 = (const float4*)row;
    const int lab = labels[b];

    // 8 threads/row: coords 0..95 as 24 float4 chunks, lane p owns {p,p+8,p+16}
    float sum_s = 0.0f;
    #pragma unroll
    for (int i = 0; i < 3; ++i) {
        const float4 yv = row4[p + 8 * i];   // lanes 0..7 -> 128 contiguous B
        float s0 = C.c[NT - 1], s1 = s0, s2 = s0, s3 = s0;
        #pragma unroll
        for (int k = NT - 2; k >= 0; --k) {
            s0 = fmaf(s0, yv.x, C.c[k]);
            s1 = fmaf(s1, yv.y, C.c[k]);
            s2 = fmaf(s2, yv.z, C.c[k]);
            s3 = fmaf(s3, yv.w, C.c[k]);
        }
        sum_s += (s0 + s1) + (s2 + s3);
    }

    // 13th polynomial: lanes p<4 -> coord 96+p, lanes p>=4 -> label coord
    const float y13 = (p < 4) ? row[96 + p] : row[lab];
    float s13 = C.c[NT - 1];
    #pragma unroll
    for (int k = NT - 2; k >= 0; --k) s13 = fmaf(s13, y13, C.c[k]);
    if (p < 4) sum_s += s13;             // coords 96..99 join the norm sum

    // reduce sum_s across the 8 lanes of this row (bits 0..2)
    sum_s += __shfl_xor(sum_s, 1);
    sum_s += __shfl_xor(sum_s, 2);
    sum_s += __shfl_xor(sum_s, 4);

    // label-poly value (held by lanes p>=4) to lanes p<4
    const float s_lab = __shfl_xor(s13, 4);

    float term = (p == 0) ? (logf(sum_s) - logf(s_lab)) : 0.0f;

    // wave butterfly over the 8 rows in this wave (bits 3..5)
    term += __shfl_xor(term, 8);
    term += __shfl_xor(term, 16);
    term += __shfl_xor(term, 32);

    __shared__ float wsum[4];
    __shared__ int   amLast;
    const int wave = tid >> 6;
    if ((tid & 63) == 0) wsum[wave] = term;
    __syncthreads();

    unsigned* cnt = (unsigned*)(ws + NBLK);
    if (tid == 0) {
        amLast = 0;
        ws[blockIdx.x] = (wsum[0] + wsum[1]) + (wsum[2] + wsum[3]);
        __threadfence();                               // release partial
        const unsigned g = blockIdx.x >> 5;            // 32 groups of 32
        unsigned o1 = atomicAdd(&cnt[g * 16], 1u);     // 64B-spaced counters
        if ((o1 & 31u) == 31u) {                       // last of my group
            __threadfence();
            unsigned o2 = atomicAdd(&cnt[512], 1u);    // master
            if ((o2 & 31u) == 31u) amLast = 1;         // last of all
        }
    }
    __syncthreads();

    if (amLast) {
        __threadfence();                               // acquire all partials
        float s = 0.0f;
        #pragma unroll
        for (int i = 0; i < 4; ++i)
            s += __hip_atomic_load(&ws[tid * 4 + i], __ATOMIC_RELAXED,
                                   __HIP_MEMORY_SCOPE_AGENT);
        s += __shfl_xor(s, 1);
        s += __shfl_xor(s, 2);
        s += __shfl_xor(s, 4);
        s += __shfl_xor(s, 8);
        s += __shfl_xor(s, 16);
        s += __shfl_xor(s, 32);
        __shared__ float w2[4];
        if ((tid & 63) == 0) w2[tid >> 6] = s;
        __syncthreads();
        if (tid == 0) out[0] = (w2[0] + w2[1]) + (w2[2] + w2[3]);
    }
}

extern "C" void kernel_launch(void* const* d_in, const int* in_sizes, int n_in,
                              void* d_out, int out_size, void* d_ws, size_t ws_size,
                              hipStream_t stream) {
    (void)in_sizes; (void)n_in; (void)out_size; (void)ws_size;
    const float* feats  = (const float*)d_in[0];
    const int*   labels = (const int*)d_in[1];
    float*       out    = (float*)d_out;
    float*       ws     = (float*)d_ws;   // partials + counters (~6.2 KB used)

    // Saw series coefficients c_n = 2^{n/2} Gamma((d+n)/2) / Gamma(d/2) / n!,
    // d = 128, computed in double on host, passed by value (capture-safe).
    Coefs C;
    for (int n = 0; n < NT; ++n) {
        const double ln = 0.5 * n * std::log(2.0)
                        + std::lgamma((128.0 + n) / 2.0)
                        - std::lgamma(64.0)
                        - std::lgamma(n + 1.0);
        C.c[n] = (float)std::exp(ln);
    }

    // 8 threads/row * 32768 rows / 256 threads = 1024 blocks (4/CU)
    agd_onepass_kernel<<<NBLK, 256, 0, stream>>>(feats, labels, ws, out, C);
}

// Round 7
// 11.409 us; speedup vs baseline: 7.3003x; 2.3203x over previous
//
#include <hip/hip_runtime.h>
#include <cmath>

// AGD loss: for each of n=32768 rows (view-major flatten of [B,2,128] features),
// evaluate the truncated Saw series at the first 100 coordinates, sum, gather
// the label coordinate's value, accumulate log(sum) - log(s_lab).
// The exp(log_Cd - 1/(2*var)) prefactor cancels between the two logs.
// NT=20 (vs reference 40): tail ~1.5e-3 abs at worst |y*sqrt(d)|~6; measured
// absmax 0.0 at NT=20 in round 4. Threshold is 2%.
//
// Structure lessons:
//  - r3: 1024 SAME-address atomicAdds serialize (~17 ns each) = +17 us.
//  - r5: cg::this_grid().sync() costs ~65 us on MI355X.
//  - r6: per-block __threadfence() (agent fence -> L2 wb/inv) costs ~15+ us.
// This round: single node, last-block-done arrival with NO fences. All
// cross-block data moves through device-scope atomic RMWs (they execute at
// the coherence point, never stale), ordered by bare `s_waitcnt vmcnt(0)`
// (waits the RMW ack; ~100ns, not an L2 writeback). Arrival counters use the
// poison-proof residue trick: "(old & 31)==31" fires exactly once per 32
// increments regardless of the counter's starting value (0xAA poison,
// correctness call, or accumulation across graph replays).

#define BQ     16384   // batch
#define NROWS  32768   // V*B
#define NT     20      // truncated series terms
#define NBLK   1024

struct Coefs { float c[NT]; };

// d_ws layout (floats): partial slot for block i at ws[i*16]  (64B stride,
// 64 KB total); counters (uints) after that: sub[g] at cnt[g*16] (g<32),
// master at cnt[512].
__global__ __launch_bounds__(256) void agd_onepass_kernel(
    const float* __restrict__ feats,    // [B, 2, 128]
    const int*   __restrict__ labels,   // [B]
    float*       __restrict__ ws,       // d_ws
    float*       __restrict__ out,      // [1]
    Coefs C)
{
    const int tid = threadIdx.x;
    const int p   = tid & 7;
    const int j   = blockIdx.x * 32 + (tid >> 3);   // global row, 32 rows/block
    const int b   = j & (BQ - 1);
    const int v   = j >> 14;
    const float*  row  = feats + ((size_t)(b * 2 + v) << 7);
    const float4* row4 = (const float4*)row;
    const int lab = labels[b];

    // 8 threads/row: coords 0..95 as 24 float4 chunks, lane p owns {p,p+8,p+16}
    float sum_s = 0.0f;
    #pragma unroll
    for (int i = 0; i < 3; ++i) {
        const float4 yv = row4[p + 8 * i];   // lanes 0..7 -> 128 contiguous B
        float s0 = C.c[NT - 1], s1 = s0, s2 = s0, s3 = s0;
        #pragma unroll
        for (int k = NT - 2; k >= 0; --k) {
            s0 = fmaf(s0, yv.x, C.c[k]);
            s1 = fmaf(s1, yv.y, C.c[k]);
            s2 = fmaf(s2, yv.z, C.c[k]);
            s3 = fmaf(s3, yv.w, C.c[k]);
        }
        sum_s += (s0 + s1) + (s2 + s3);
    }

    // 13th polynomial: lanes p<4 -> coord 96+p, lanes p>=4 -> label coord
    const float y13 = (p < 4) ? row[96 + p] : row[lab];
    float s13 = C.c[NT - 1];
    #pragma unroll
    for (int k = NT - 2; k >= 0; --k) s13 = fmaf(s13, y13, C.c[k]);
    if (p < 4) sum_s += s13;             // coords 96..99 join the norm sum

    // reduce sum_s across the 8 lanes of this row (bits 0..2)
    sum_s += __shfl_xor(sum_s, 1);
    sum_s += __shfl_xor(sum_s, 2);
    sum_s += __shfl_xor(sum_s, 4);

    // label-poly value (held by lanes p>=4) to lanes p<4
    const float s_lab = __shfl_xor(s13, 4);

    float term = (p == 0) ? (logf(sum_s) - logf(s_lab)) : 0.0f;

    // wave butterfly over the 8 rows in this wave (bits 3..5)
    term += __shfl_xor(term, 8);
    term += __shfl_xor(term, 16);
    term += __shfl_xor(term, 32);

    __shared__ float wsum[4];
    __shared__ int   amLast;
    const int wave = tid >> 6;
    if ((tid & 63) == 0) wsum[wave] = term;
    if (tid == 0) amLast = 0;
    __syncthreads();

    unsigned* cnt = (unsigned*)(ws + NBLK * 16);
    if (tid == 0) {
        const float part = (wsum[0] + wsum[1]) + (wsum[2] + wsum[3]);
        // publish partial via device-scope RMW (coherence point, never stale)
        atomicExch(&ws[blockIdx.x * 16], part);
        // exchange committed before the flag increment
        asm volatile("s_waitcnt vmcnt(0)" ::: "memory");
        const unsigned g = blockIdx.x >> 5;            // 32 groups of 32
        unsigned o1 = atomicAdd(&cnt[g * 16], 1u);
        if ((o1 & 31u) == 31u) {                       // last of my group
            asm volatile("s_waitcnt vmcnt(0)" ::: "memory");
            unsigned o2 = atomicAdd(&cnt[512], 1u);    // master
            if ((o2 & 31u) == 31u) amLast = 1;         // last of all
        }
    }
    __syncthreads();

    if (amLast) {
        // coherent read-back of the 1024 partials: fetch_add(0) RMWs
        float s = 0.0f;
        #pragma unroll
        for (int i = 0; i < 4; ++i)
            s += atomicAdd(&ws[(tid * 4 + i) * 16], 0.0f);
        s += __shfl_xor(s, 1);
        s += __shfl_xor(s, 2);
        s += __shfl_xor(s, 4);
        s += __shfl_xor(s, 8);
        s += __shfl_xor(s, 16);
        s += __shfl_xor(s, 32);
        __shared__ float w2[4];
        if ((tid & 63) == 0) w2[tid >> 6] = s;
        __syncthreads();
        if (tid == 0) out[0] = (w2[0] + w2[1]) + (w2[2] + w2[3]);
    }
}

extern "C" void kernel_launch(void* const* d_in, const int* in_sizes, int n_in,
                              void* d_out, int out_size, void* d_ws, size_t ws_size,
                              hipStream_t stream) {
    (void)in_sizes; (void)n_in; (void)out_size; (void)ws_size;
    const float* feats  = (const float*)d_in[0];
    const int*   labels = (const int*)d_in[1];
    float*       out    = (float*)d_out;
    float*       ws     = (float*)d_ws;   // ~66 KB used

    // Saw series coefficients c_n = 2^{n/2} Gamma((d+n)/2) / Gamma(d/2) / n!,
    // d = 128, computed in double on host, passed by value (capture-safe).
    Coefs C;
    for (int n = 0; n < NT; ++n) {
        const double ln = 0.5 * n * std::log(2.0)
                        + std::lgamma((128.0 + n) / 2.0)
                        - std::lgamma(64.0)
                        - std::lgamma(n + 1.0);
        C.c[n] = (float)std::exp(ln);
    }

    // 8 threads/row * 32768 rows / 256 threads = 1024 blocks (4/CU)
    agd_onepass_kernel<<<NBLK, 256, 0, stream>>>(feats, labels, ws, out, C);
}